// Round 9
// baseline (104.730 us; speedup 1.0000x reference)
//
#include <hip/hip_runtime.h>
#include <math.h>

// BDH recurrence, 6-kernel fused pipeline; fp16 MFMA GEMMs (f32 accum),
// on-the-fly f32->f16 conversion in GEMM staging, double-buffered LDS.
//  K1 xu = relu(emb @ Dx^T) + rowsum partials + fused LN^T(emb)   (8,32)
//  K2 x-scan (inline normalizer scan from Spart)                  512
//  K3 W = causal-decay mask . (X X^T)  batched                    (4,4,8)
//  K4 aln = LN(W @ lnv)  batched, full-row tile                   (4,8)
//  K5 y = relu(aln @ Dy^T) * x                                    (8,32)
//  K6 out = LN(y @ E^T), full-row tile                            32

#define TT 256
#define BB 8
#define DD 256
#define NN 1024
#define ROWS (BB*TT)   // 2048

using f16   = _Float16;
using f16x4 = __attribute__((ext_vector_type(4))) _Float16;
using f16x8 = __attribute__((ext_vector_type(8))) _Float16;
using f32x4 = __attribute__((ext_vector_type(4))) float;

__device__ inline f32x4 mfma16(f16x8 a, f16x8 b, f32x4 c) {
    return __builtin_amdgcn_mfma_f32_16x16x32_f16(a, b, c, 0, 0, 0);
}
__device__ inline f16x8 cvt8(float4 a, float4 b) {
    f16x8 r = {(f16)a.x, (f16)a.y, (f16)a.z, (f16)a.w,
               (f16)b.x, (f16)b.y, (f16)b.z, (f16)b.w};
    return r;
}

// ===== K1: xu = relu(emb @ Dx^T), 64x128 tile, f32 inputs, + Spart + lnT ===
__launch_bounds__(256)
__global__ void k_xu(const float* __restrict__ emb, const float* __restrict__ Dx,
                     float* __restrict__ xu, float* __restrict__ Spart,
                     f16* __restrict__ lnvTf) {
    const int i0 = blockIdx.y * 64, j0 = blockIdx.x * 128;
    const int t = threadIdx.x, lane = t & 63, wid = t >> 6;
    const int wr = wid >> 1, wc = wid & 1;
    const int lr = lane >> 4, lc = lane & 15;
    __shared__ __align__(16) char lds[30720];
    auto sA = (f16 (*)[64][40])lds;            // [2][64][40] = 10240 B
    auto sB = (f16 (*)[128][40])(lds + 10240); // [2][128][40] = 20480 B
    auto sT = (f16 (*)[72])lds;                // [128][72] = 18432 B (post-loop)
    __shared__ float ssum[64][2];
    const int arow = t >> 2, akq = (t & 3) * 8;
    f32x4 acc[2][4];
    const f32x4 z4 = {0.f, 0.f, 0.f, 0.f};
#pragma unroll
    for (int fi = 0; fi < 2; ++fi)
#pragma unroll
        for (int fj = 0; fj < 4; ++fj) acc[fi][fj] = z4;

    const int NT = DD / 32;  // 8
    const float* pa  = emb + (size_t)(i0 + arow) * DD + akq;
    const float* pb0 = Dx  + (size_t)(j0 + arow) * DD + akq;
    const float* pb1 = Dx  + (size_t)(j0 + 64 + arow) * DD + akq;
    float4 va0 = *(const float4*)pa,        va1 = *(const float4*)(pa + 4);
    float4 vb00 = *(const float4*)pb0,      vb01 = *(const float4*)(pb0 + 4);
    float4 vb10 = *(const float4*)pb1,      vb11 = *(const float4*)(pb1 + 4);
    *(f16x8*)&sA[0][arow][akq]      = cvt8(va0, va1);
    *(f16x8*)&sB[0][arow][akq]      = cvt8(vb00, vb01);
    *(f16x8*)&sB[0][64 + arow][akq] = cvt8(vb10, vb11);
    __syncthreads();
    int cur = 0;
    for (int kt = 0; kt < NT; ++kt) {
        if (kt + 1 < NT) {
            int ko = (kt + 1) * 32;
            va0  = *(const float4*)(pa + ko);  va1  = *(const float4*)(pa + ko + 4);
            vb00 = *(const float4*)(pb0 + ko); vb01 = *(const float4*)(pb0 + ko + 4);
            vb10 = *(const float4*)(pb1 + ko); vb11 = *(const float4*)(pb1 + ko + 4);
        }
        f16x8 ah[2], bh[4];
#pragma unroll
        for (int fi = 0; fi < 2; ++fi)
            ah[fi] = *(const f16x8*)&sA[cur][wr * 32 + fi * 16 + lc][lr * 8];
#pragma unroll
        for (int fj = 0; fj < 4; ++fj)
            bh[fj] = *(const f16x8*)&sB[cur][wc * 64 + fj * 16 + lc][lr * 8];
#pragma unroll
        for (int fi = 0; fi < 2; ++fi)
#pragma unroll
            for (int fj = 0; fj < 4; ++fj)
                acc[fi][fj] = mfma16(ah[fi], bh[fj], acc[fi][fj]);
        if (kt + 1 < NT) {
            *(f16x8*)&sA[cur ^ 1][arow][akq]      = cvt8(va0, va1);
            *(f16x8*)&sB[cur ^ 1][arow][akq]      = cvt8(vb00, vb01);
            *(f16x8*)&sB[cur ^ 1][64 + arow][akq] = cvt8(vb10, vb11);
            __syncthreads();
            cur ^= 1;
        }
    }
    // epilogue: relu -> xu f32, row-sum partials
    float rs[2][4] = {};
#pragma unroll
    for (int fi = 0; fi < 2; ++fi)
#pragma unroll
        for (int fj = 0; fj < 4; ++fj) {
            f32x4 d = acc[fi][fj];
#pragma unroll
            for (int r = 0; r < 4; ++r) {
                int i = i0 + wr * 32 + fi * 16 + lr * 4 + r;
                int j = j0 + wc * 64 + fj * 16 + lc;
                float vv = fmaxf(d[r], 0.f);
                xu[(size_t)i * NN + j] = vv;
                rs[fi][r] += vv;
            }
        }
#pragma unroll
    for (int fi = 0; fi < 2; ++fi)
#pragma unroll
        for (int r = 0; r < 4; ++r) {
            float v = rs[fi][r];
#pragma unroll
            for (int m = 1; m < 16; m <<= 1) v += __shfl_xor(v, m, 64);
            if (lc == 0) ssum[wr * 32 + fi * 16 + lr * 4 + r][wc] = v;
        }
    __syncthreads();
    if (t < 64) Spart[(size_t)blockIdx.x * ROWS + i0 + t] = ssum[t][0] + ssum[t][1];

    // fused LN^T(emb) for this M-tile's 64 rows (only one block per M-tile)
    if (blockIdx.x == 0) {
        const int b = i0 >> 8, tbase = i0 & 255;
        for (int half = 0; half < 2; ++half) {
            __syncthreads();
            for (int rr = 0; rr < 16; ++rr) {
                int tloc = wid * 16 + rr;
                const float* p = emb + (size_t)(i0 + tloc) * DD + lane * 4;
                float4 v = *(const float4*)p;
                float s  = v.x + v.y + v.z + v.w;
                float s2 = v.x*v.x + v.y*v.y + v.z*v.z + v.w*v.w;
#pragma unroll
                for (int o = 32; o; o >>= 1) {
                    s  += __shfl_xor(s,  o, 64);
                    s2 += __shfl_xor(s2, o, 64);
                }
                float m  = s * (1.0f / 256.0f);
                float sc = rsqrtf(s2 * (1.0f / 256.0f) - m * m + 1e-5f);
                if ((lane >> 5) == half) {
                    int jloc = (lane & 31) * 4;
                    sT[jloc + 0][tloc] = (f16)((v.x - m) * sc);
                    sT[jloc + 1][tloc] = (f16)((v.y - m) * sc);
                    sT[jloc + 2][tloc] = (f16)((v.z - m) * sc);
                    sT[jloc + 3][tloc] = (f16)((v.w - m) * sc);
                }
            }
            __syncthreads();
            int jl = t & 127, th = t >> 7;
            size_t o = ((size_t)b * DD + half * 128 + jl) * TT + tbase + th * 32;
#pragma unroll
            for (int q = 0; q < 4; ++q)
                *(f16x8*)(lnvTf + o + q * 8) = *(const f16x8*)&sT[jl][th * 32 + q * 8];
        }
    }
}

// ===== K2: x-scan with inline normalizer computation =======================
__launch_bounds__(256)
__global__ void k_xscan(const float* __restrict__ xu, const float* __restrict__ Spart,
                        f16* __restrict__ xf) {
    __shared__ float Gs[16][16], Hs[16][16], Cs[16][16];
    __shared__ float sS[256], sRC[256];
    __shared__ int bad;
    const int b = blockIdx.x >> 6, jgrp = blockIdx.x & 63;
    const int tid = threadIdx.x;
    // normalizer: sigma_t = 1 exactly when us_t >= eps (relu sums), so
    // us_t = 0.97 + S_t; validated, with exact serial fallback.
    float s = 0.f;
#pragma unroll
    for (int g = 0; g < 8; ++g) s += Spart[(size_t)g * ROWS + b * TT + tid];
    if (tid == 0) bad = 0;
    sS[tid] = s;
    __syncthreads();
    float us = (tid == 0) ? s : (0.97f + s);
    if (us < 1e-12f) bad = 1;
    __syncthreads();
    if (!bad) {
        sRC[tid] = 1.0f / us;
    } else if (tid == 0) {
        float sigma = 0.f;
        for (int tt = 0; tt < TT; ++tt) {
            float u2 = fmaf(0.97f, sigma, sS[tt]);
            float r  = 1.0f / fmaxf(u2, 1e-12f);
            sRC[tt] = r;
            sigma = u2 * r;
        }
    }
    __syncthreads();

    const int ck = tid >> 4, jl = tid & 15;
    const int j  = jgrp * 16 + jl;
    const size_t base = ((size_t)b * TT + ck * 16) * NN + j;
    float xur[16], rcr[16];
#pragma unroll
    for (int i = 0; i < 16; ++i) xur[i] = xu[base + (size_t)i * NN];
#pragma unroll
    for (int i = 0; i < 16; ++i) rcr[i] = sRC[ck * 16 + i];
    float xs = 0.f, G = 1.f;
#pragma unroll
    for (int i = 0; i < 16; ++i) {
        xs = fmaf(0.97f, xs, xur[i]) * rcr[i];
        G *= 0.97f * rcr[i];
    }
    Gs[ck][jl] = G;
    Hs[ck][jl] = xs;
    __syncthreads();
    if (tid < 16) {
        float cr = 0.f;
        Cs[0][tid] = 0.f;
#pragma unroll
        for (int cc = 0; cc < 15; ++cc) {
            cr = fmaf(Gs[cc][tid], cr, Hs[cc][tid]);
            Cs[cc + 1][tid] = cr;
        }
    }
    __syncthreads();
    xs = Cs[ck][jl];
#pragma unroll
    for (int i = 0; i < 16; ++i) {
        xs = fmaf(0.97f, xs, xur[i]) * rcr[i];
        xf[base + (size_t)i * NN] = (f16)xs;
    }
}

// ===== K3: W = causal-decay mask . (X X^T), 64x64 tile, batched ============
__launch_bounds__(256)
__global__ void k_W(const f16* __restrict__ xf, f16* __restrict__ Wf) {
    const int b = blockIdx.z;
    const f16* X = xf + (size_t)b * TT * NN;
    f16* Wb = Wf + (size_t)b * TT * TT;
    const int i0 = blockIdx.y * 64, j0 = blockIdx.x * 64;
    const int t = threadIdx.x, lane = t & 63, wid = t >> 6;
    const int wr = wid >> 1, wc = wid & 1;
    const int lr = lane >> 4, lc = lane & 15;
    const float L2D = -0.043943348f;  // log2(0.97)

    if (j0 > i0) {  // fully-masked tile
#pragma unroll
        for (int fi = 0; fi < 2; ++fi)
#pragma unroll
            for (int fj = 0; fj < 2; ++fj)
#pragma unroll
                for (int r = 0; r < 4; ++r) {
                    int i = i0 + wr * 32 + fi * 16 + lr * 4 + r;
                    int j = j0 + wc * 32 + fj * 16 + lc;
                    Wb[(size_t)i * TT + j] = (f16)0.f;
                }
        return;
    }

    __shared__ __align__(16) f16 sA[2][64][40], sB[2][64][40];
    const int srow = t >> 2, skq = (t & 3) * 8;
    f32x4 acc[2][2];
    const f32x4 z4 = {0.f, 0.f, 0.f, 0.f};
    acc[0][0] = z4; acc[0][1] = z4; acc[1][0] = z4; acc[1][1] = z4;

    const int NT = NN / 32;  // 32
    const f16* pa = X + (size_t)(i0 + srow) * NN + skq;
    const f16* pb = X + (size_t)(j0 + srow) * NN + skq;
    f16x8 va = *(const f16x8*)pa;
    f16x8 vb = *(const f16x8*)pb;
    *(f16x8*)&sA[0][srow][skq] = va;
    *(f16x8*)&sB[0][srow][skq] = vb;
    __syncthreads();
    int cur = 0;
    for (int kt = 0; kt < NT; ++kt) {
        if (kt + 1 < NT) {
            va = *(const f16x8*)(pa + (kt + 1) * 32);
            vb = *(const f16x8*)(pb + (kt + 1) * 32);
        }
        f16x8 ah0 = *(const f16x8*)&sA[cur][wr * 32 + lc][lr * 8];
        f16x8 ah1 = *(const f16x8*)&sA[cur][wr * 32 + 16 + lc][lr * 8];
        f16x8 bh0 = *(const f16x8*)&sB[cur][wc * 32 + lc][lr * 8];
        f16x8 bh1 = *(const f16x8*)&sB[cur][wc * 32 + 16 + lc][lr * 8];
        acc[0][0] = mfma16(ah0, bh0, acc[0][0]);
        acc[0][1] = mfma16(ah0, bh1, acc[0][1]);
        acc[1][0] = mfma16(ah1, bh0, acc[1][0]);
        acc[1][1] = mfma16(ah1, bh1, acc[1][1]);
        if (kt + 1 < NT) {
            *(f16x8*)&sA[cur ^ 1][srow][skq] = va;
            *(f16x8*)&sB[cur ^ 1][srow][skq] = vb;
            __syncthreads();
            cur ^= 1;
        }
    }
#pragma unroll
    for (int fi = 0; fi < 2; ++fi)
#pragma unroll
        for (int fj = 0; fj < 2; ++fj) {
            f32x4 d = acc[fi][fj];
#pragma unroll
            for (int r = 0; r < 4; ++r) {
                int i = i0 + wr * 32 + fi * 16 + lr * 4 + r;
                int j = j0 + wc * 32 + fj * 16 + lc;
                float w = 0.f;
                if (j < i) w = exp2f((float)(i - 1 - j) * L2D) * d[r];
                Wb[(size_t)i * TT + j] = (f16)w;
            }
        }
}

// ===== K4: aln = LN(W @ lnv), 64x256 tile (full row), batched ==============
__launch_bounds__(256)
__global__ void k_a(const f16* __restrict__ Wf, const f16* __restrict__ lnvTf,
                    f16* __restrict__ alnf) {
    const int mt = blockIdx.x, b = blockIdx.y;
    const int i0 = mt * 64;
    const f16* A = Wf + (size_t)b * TT * TT;
    const f16* B = lnvTf + (size_t)b * DD * TT;
    const int t = threadIdx.x, lane = t & 63, w = t >> 6;
    const int lr = lane >> 4, lc = lane & 15;
    __shared__ __align__(16) char lds[51200];
    auto sA = (f16 (*)[64][40])lds;             // [2][64][40]
    auto sB = (f16 (*)[256][40])(lds + 10240);  // [2][256][40]
    auto sO = (f16 (*)[264])lds;                // [64][264] (post-loop)
    const int arow = t >> 2, akq = (t & 3) * 8;
    f32x4 acc[16];
    const f32x4 z4 = {0.f, 0.f, 0.f, 0.f};
#pragma unroll
    for (int fj = 0; fj < 16; ++fj) acc[fj] = z4;

    const int NT = TT / 32;  // 8
    const f16* pa = A + (size_t)(i0 + arow) * TT + akq;
    const f16* pb = B + (size_t)arow * TT + akq;
    f16x8 va  = *(const f16x8*)pa;
    f16x8 vb0 = *(const f16x8*)(pb);
    f16x8 vb1 = *(const f16x8*)(pb + 64 * TT);
    f16x8 vb2 = *(const f16x8*)(pb + 128 * TT);
    f16x8 vb3 = *(const f16x8*)(pb + 192 * TT);
    *(f16x8*)&sA[0][arow][akq]       = va;
    *(f16x8*)&sB[0][arow][akq]       = vb0;
    *(f16x8*)&sB[0][64 + arow][akq]  = vb1;
    *(f16x8*)&sB[0][128 + arow][akq] = vb2;
    *(f16x8*)&sB[0][192 + arow][akq] = vb3;
    __syncthreads();
    int cur = 0;
    for (int kt = 0; kt < NT; ++kt) {
        if (kt + 1 < NT) {
            int ko = (kt + 1) * 32;
            va  = *(const f16x8*)(pa + ko);
            vb0 = *(const f16x8*)(pb + ko);
            vb1 = *(const f16x8*)(pb + 64 * TT + ko);
            vb2 = *(const f16x8*)(pb + 128 * TT + ko);
            vb3 = *(const f16x8*)(pb + 192 * TT + ko);
        }
        f16x8 af = *(const f16x8*)&sA[cur][w * 16 + lc][lr * 8];
#pragma unroll
        for (int fj = 0; fj < 16; ++fj) {
            f16x8 bf = *(const f16x8*)&sB[cur][fj * 16 + lc][lr * 8];
            acc[fj] = mfma16(af, bf, acc[fj]);
        }
        if (kt + 1 < NT) {
            *(f16x8*)&sA[cur ^ 1][arow][akq]       = va;
            *(f16x8*)&sB[cur ^ 1][arow][akq]       = vb0;
            *(f16x8*)&sB[cur ^ 1][64 + arow][akq]  = vb1;
            *(f16x8*)&sB[cur ^ 1][128 + arow][akq] = vb2;
            *(f16x8*)&sB[cur ^ 1][192 + arow][akq] = vb3;
            __syncthreads();
            cur ^= 1;
        }
    }
    // row LN (rows fully within wave)
    float s[4] = {}, s2[4] = {};
#pragma unroll
    for (int fj = 0; fj < 16; ++fj)
#pragma unroll
        for (int r = 0; r < 4; ++r) { float v = acc[fj][r]; s[r] += v; s2[r] += v * v; }
#pragma unroll
    for (int m = 1; m < 16; m <<= 1)
#pragma unroll
        for (int r = 0; r < 4; ++r) {
            s[r]  += __shfl_xor(s[r],  m, 64);
            s2[r] += __shfl_xor(s2[r], m, 64);
        }
    float mean[4], rstd[4];
#pragma unroll
    for (int r = 0; r < 4; ++r) {
        mean[r] = s[r] * (1.f / 256.f);
        rstd[r] = rsqrtf(s2[r] * (1.f / 256.f) - mean[r] * mean[r] + 1e-5f);
    }
    __syncthreads();
#pragma unroll
    for (int fj = 0; fj < 16; ++fj)
#pragma unroll
        for (int r = 0; r < 4; ++r)
            sO[w * 16 + lr * 4 + r][fj * 16 + lc] = (f16)((acc[fj][r] - mean[r]) * rstd[r]);
    __syncthreads();
    int row = t >> 2, c0 = (t & 3) * 64;
    size_t o = ((size_t)(b * TT + i0 + row)) * DD + c0;
#pragma unroll
    for (int q = 0; q < 8; ++q)
        *(f16x8*)(alnf + o + q * 8) = *(const f16x8*)&sO[row][c0 + q * 8];
}

// ===== K5: y = relu(aln @ Dy^T) * x, 64x128 tile, Dy f32 on-the-fly ========
__launch_bounds__(256)
__global__ void k_y(const f16* __restrict__ alnf, const float* __restrict__ Dy,
                    f16* __restrict__ yf, const f16* __restrict__ xf) {
    const int i0 = blockIdx.y * 64, j0 = blockIdx.x * 128;
    const int t = threadIdx.x, lane = t & 63, wid = t >> 6;
    const int wr = wid >> 1, wc = wid & 1;
    const int lr = lane >> 4, lc = lane & 15;
    __shared__ __align__(16) f16 sA[2][64][40], sB[2][128][40];
    const int arow = t >> 2, akq = (t & 3) * 8;
    f32x4 acc[2][4];
    const f32x4 z4 = {0.f, 0.f, 0.f, 0.f};
#pragma unroll
    for (int fi = 0; fi < 2; ++fi)
#pragma unroll
        for (int fj = 0; fj < 4; ++fj) acc[fi][fj] = z4;

    const int NT = DD / 32;  // 8
    const f16*   pa  = alnf + (size_t)(i0 + arow) * DD + akq;
    const float* pb0 = Dy + (size_t)(j0 + arow) * DD + akq;
    const float* pb1 = Dy + (size_t)(j0 + 64 + arow) * DD + akq;
    f16x8  va   = *(const f16x8*)pa;
    float4 vb00 = *(const float4*)pb0, vb01 = *(const float4*)(pb0 + 4);
    float4 vb10 = *(const float4*)pb1, vb11 = *(const float4*)(pb1 + 4);
    *(f16x8*)&sA[0][arow][akq]      = va;
    *(f16x8*)&sB[0][arow][akq]      = cvt8(vb00, vb01);
    *(f16x8*)&sB[0][64 + arow][akq] = cvt8(vb10, vb11);
    __syncthreads();
    int cur = 0;
    for (int kt = 0; kt < NT; ++kt) {
        if (kt + 1 < NT) {
            int ko = (kt + 1) * 32;
            va   = *(const f16x8*)(pa + ko);
            vb00 = *(const float4*)(pb0 + ko); vb01 = *(const float4*)(pb0 + ko + 4);
            vb10 = *(const float4*)(pb1 + ko); vb11 = *(const float4*)(pb1 + ko + 4);
        }
        f16x8 ah[2], bh[4];
#pragma unroll
        for (int fi = 0; fi < 2; ++fi)
            ah[fi] = *(const f16x8*)&sA[cur][wr * 32 + fi * 16 + lc][lr * 8];
#pragma unroll
        for (int fj = 0; fj < 4; ++fj)
            bh[fj] = *(const f16x8*)&sB[cur][wc * 64 + fj * 16 + lc][lr * 8];
#pragma unroll
        for (int fi = 0; fi < 2; ++fi)
#pragma unroll
            for (int fj = 0; fj < 4; ++fj)
                acc[fi][fj] = mfma16(ah[fi], bh[fj], acc[fi][fj]);
        if (kt + 1 < NT) {
            *(f16x8*)&sA[cur ^ 1][arow][akq]      = va;
            *(f16x8*)&sB[cur ^ 1][arow][akq]      = cvt8(vb00, vb01);
            *(f16x8*)&sB[cur ^ 1][64 + arow][akq] = cvt8(vb10, vb11);
            __syncthreads();
            cur ^= 1;
        }
    }
#pragma unroll
    for (int fi = 0; fi < 2; ++fi)
#pragma unroll
        for (int fj = 0; fj < 4; ++fj) {
            f32x4 d = acc[fi][fj];
#pragma unroll
            for (int r = 0; r < 4; ++r) {
                int i = i0 + wr * 32 + fi * 16 + lr * 4 + r;
                int j = j0 + wc * 64 + fj * 16 + lc;
                size_t o = (size_t)i * NN + j;
                float vv = fmaxf(d[r], 0.f) * (float)xf[o];
                yf[o] = (f16)vv;
            }
        }
}

// ===== K6: out = LN(y @ E^T), 64x256 tile (full row), E f32 on-the-fly =====
__launch_bounds__(256)
__global__ void k_v(const f16* __restrict__ yf, const float* __restrict__ E,
                    float* __restrict__ out) {
    const int i0 = blockIdx.x * 64;
    const int t = threadIdx.x, lane = t & 63, w = t >> 6;
    const int lr = lane >> 4, lc = lane & 15;
    __shared__ __align__(16) char lds[51200];
    auto sA = (f16 (*)[64][40])lds;             // [2][64][40]
    auto sB = (f16 (*)[256][40])(lds + 10240);  // [2][256][40]
    auto sO = (f16 (*)[264])lds;                // [64][264] (post-loop)
    const int arow = t >> 2, akq = (t & 3) * 8;
    f32x4 acc[16];
    const f32x4 z4 = {0.f, 0.f, 0.f, 0.f};
#pragma unroll
    for (int fj = 0; fj < 16; ++fj) acc[fj] = z4;

    const int NT = NN / 32;  // 32
    const f16*   pa = yf + (size_t)(i0 + arow) * NN + akq;
    const float* pb = E + (size_t)arow * NN + akq;   // rows arow + r*64
    f16x8  va = *(const f16x8*)pa;
    float4 vb[4][2];
#pragma unroll
    for (int rI = 0; rI < 4; ++rI) {
        vb[rI][0] = *(const float4*)(pb + (size_t)rI * 64 * NN);
        vb[rI][1] = *(const float4*)(pb + (size_t)rI * 64 * NN + 4);
    }
    *(f16x8*)&sA[0][arow][akq] = va;
#pragma unroll
    for (int rI = 0; rI < 4; ++rI)
        *(f16x8*)&sB[0][rI * 64 + arow][akq] = cvt8(vb[rI][0], vb[rI][1]);
    __syncthreads();
    int cur = 0;
    for (int kt = 0; kt < NT; ++kt) {
        if (kt + 1 < NT) {
            int ko = (kt + 1) * 32;
            va = *(const f16x8*)(pa + ko);
#pragma unroll
            for (int rI = 0; rI < 4; ++rI) {
                vb[rI][0] = *(const float4*)(pb + (size_t)rI * 64 * NN + ko);
                vb[rI][1] = *(const float4*)(pb + (size_t)rI * 64 * NN + ko + 4);
            }
        }
        f16x8 af = *(const f16x8*)&sA[cur][w * 16 + lc][lr * 8];
#pragma unroll
        for (int fj = 0; fj < 16; ++fj) {
            f16x8 bf = *(const f16x8*)&sB[cur][fj * 16 + lc][lr * 8];
            acc[fj] = mfma16(af, bf, acc[fj]);
        }
        if (kt + 1 < NT) {
            *(f16x8*)&sA[cur ^ 1][arow][akq] = va;
#pragma unroll
            for (int rI = 0; rI < 4; ++rI)
                *(f16x8*)&sB[cur ^ 1][rI * 64 + arow][akq] = cvt8(vb[rI][0], vb[rI][1]);
            __syncthreads();
            cur ^= 1;
        }
    }
    // row LN
    float s[4] = {}, s2[4] = {};
#pragma unroll
    for (int fj = 0; fj < 16; ++fj)
#pragma unroll
        for (int r = 0; r < 4; ++r) { float v = acc[fj][r]; s[r] += v; s2[r] += v * v; }
#pragma unroll
    for (int m = 1; m < 16; m <<= 1)
#pragma unroll
        for (int r = 0; r < 4; ++r) {
            s[r]  += __shfl_xor(s[r],  m, 64);
            s2[r] += __shfl_xor(s2[r], m, 64);
        }
    float mean[4], rstd[4];
#pragma unroll
    for (int r = 0; r < 4; ++r) {
        mean[r] = s[r] * (1.f / 256.f);
        rstd[r] = rsqrtf(s2[r] * (1.f / 256.f) - mean[r] * mean[r] + 1e-5f);
    }
    __syncthreads();
#pragma unroll
    for (int fj = 0; fj < 16; ++fj)
#pragma unroll
        for (int r = 0; r < 4; ++r)
            sO[w * 16 + lr * 4 + r][fj * 16 + lc] = (f16)((acc[fj][r] - mean[r]) * rstd[r]);
    __syncthreads();
    int row = t >> 2, c0 = (t & 3) * 64;
    size_t o = (size_t)(i0 + row) * DD + c0;
#pragma unroll
    for (int q = 0; q < 8; ++q) {
        f16x8 hv = *(const f16x8*)&sO[row][c0 + q * 8];
        float4 lo = {(float)hv[0], (float)hv[1], (float)hv[2], (float)hv[3]};
        float4 hi = {(float)hv[4], (float)hv[5], (float)hv[6], (float)hv[7]};
        *(float4*)(out + o + q * 8)     = lo;
        *(float4*)(out + o + q * 8 + 4) = hi;
    }
}

extern "C" void kernel_launch(void* const* d_in, const int* in_sizes, int n_in,
                              void* d_out, int out_size, void* d_ws, size_t ws_size,
                              hipStream_t stream) {
    (void)in_sizes; (void)n_in; (void)out_size; (void)ws_size;
    const float* emb = (const float*)d_in[0];   // (B,T,d)
    const float* E   = (const float*)d_in[1];   // (d,n)
    const float* Dx  = (const float*)d_in[2];   // (n,d)
    const float* Dy  = (const float*)d_in[3];   // (n,d)
    float* out = (float*)d_out;                 // (B,T,d)

    char* wsb = (char*)d_ws;
    f16*   lnvTf = (f16*)(wsb + 0);           // 1 MB   [b][j][t]
    f16*   xf    = (f16*)(wsb + 1048576);     // 4 MB   [b*t][n]
    f16*   Wf    = (f16*)(wsb + 5242880);     // 1 MB   [b][t][s]
    f16*   alnf  = (f16*)(wsb + 6291456);     // 1 MB
    f16*   yf    = (f16*)(wsb + 7340032);     // 4 MB
    float* xu    = (float*)(wsb + 11534336);  // 8 MB
    float* Spart = (float*)(wsb + 19922944);  // 64 KB (8 x ROWS)

    // K1: xu GEMM + rowsum partials + fused LN^T(emb)
    k_xu<<<dim3(NN / 128, ROWS / 64), 256, 0, stream>>>(emb, Dx, xu, Spart, lnvTf);
    // K2: x scan (inline normalizer)
    k_xscan<<<BB * (NN / 16), 256, 0, stream>>>(xu, Spart, xf);
    // K3: W = mask . (X X^T)
    k_W<<<dim3(TT / 64, TT / 64, BB), 256, 0, stream>>>(xf, Wf);
    // K4: aln = LN(W @ lnv)
    k_a<<<dim3(TT / 64, BB), 256, 0, stream>>>(Wf, lnvTf, alnf);
    // K5: y = relu(aln @ Dy^T) * x
    k_y<<<dim3(NN / 128, ROWS / 64), 256, 0, stream>>>(alnf, Dy, yf, xf);
    // K6: out = LN(y @ E^T)
    k_v<<<ROWS / 64, 256, 0, stream>>>(yf, E, out);
}

// Round 10
// 80.330 us; speedup vs baseline: 1.3038x; 1.3038x over previous
//
#include <hip/hip_runtime.h>
#include <math.h>

// BDH recurrence, 8-kernel pipeline; fp16 MFMA GEMMs (f32 accum),
// on-the-fly f32->f16 conversion in staging, double-buffered LDS.
//  K1 xu = relu(emb @ Dx^T) + rowsum partials + fused LN^T(emb)   (8,32)
//  K2 x-scan (inline normalizer)                                  512
//  K3 W = causal-decay mask . (X X^T)  batched                    (4,4,8)
//  K4 a = W @ lnv  batched 64x64                                  (4,4,8)
//  K5 aln = LN(a) -> f16                                          512
//  K6 y = relu(aln @ Dy^T) * x                                    (8,32)
//  K7 vpart = y @ E^T  split-K=2                                  (4,32,2)
//  K8 out = LN(vpart0+vpart1)                                     512

#define TT 256
#define BB 8
#define DD 256
#define NN 1024
#define ROWS (BB*TT)   // 2048

using f16   = _Float16;
using f16x4 = __attribute__((ext_vector_type(4))) _Float16;
using f16x8 = __attribute__((ext_vector_type(8))) _Float16;
using f32x4 = __attribute__((ext_vector_type(4))) float;

__device__ inline f32x4 mfma16(f16x8 a, f16x8 b, f32x4 c) {
    return __builtin_amdgcn_mfma_f32_16x16x32_f16(a, b, c, 0, 0, 0);
}
__device__ inline f16x8 cvt8(float4 a, float4 b) {
    f16x8 r = {(f16)a.x, (f16)a.y, (f16)a.z, (f16)a.w,
               (f16)b.x, (f16)b.y, (f16)b.z, (f16)b.w};
    return r;
}

// ===== K1: xu = relu(emb @ Dx^T), 64x128 tile, f32 inputs, + Spart + lnT ===
__launch_bounds__(256)
__global__ void k_xu(const float* __restrict__ emb, const float* __restrict__ Dx,
                     float* __restrict__ xu, float* __restrict__ Spart,
                     f16* __restrict__ lnvTf) {
    const int i0 = blockIdx.y * 64, j0 = blockIdx.x * 128;
    const int t = threadIdx.x, lane = t & 63, wid = t >> 6;
    const int wr = wid >> 1, wc = wid & 1;
    const int lr = lane >> 4, lc = lane & 15;
    __shared__ __align__(16) char lds[30720];
    auto sA = (f16 (*)[64][40])lds;            // [2][64][40] = 10240 B
    auto sB = (f16 (*)[128][40])(lds + 10240); // [2][128][40] = 20480 B
    auto sT = (f16 (*)[72])lds;                // [128][72] = 18432 B (post-loop)
    __shared__ float ssum[64][2];
    const int arow = t >> 2, akq = (t & 3) * 8;
    f32x4 acc[2][4];
    const f32x4 z4 = {0.f, 0.f, 0.f, 0.f};
#pragma unroll
    for (int fi = 0; fi < 2; ++fi)
#pragma unroll
        for (int fj = 0; fj < 4; ++fj) acc[fi][fj] = z4;

    const int NT = DD / 32;  // 8
    const float* pa  = emb + (size_t)(i0 + arow) * DD + akq;
    const float* pb0 = Dx  + (size_t)(j0 + arow) * DD + akq;
    const float* pb1 = Dx  + (size_t)(j0 + 64 + arow) * DD + akq;
    float4 va0 = *(const float4*)pa,        va1 = *(const float4*)(pa + 4);
    float4 vb00 = *(const float4*)pb0,      vb01 = *(const float4*)(pb0 + 4);
    float4 vb10 = *(const float4*)pb1,      vb11 = *(const float4*)(pb1 + 4);
    *(f16x8*)&sA[0][arow][akq]      = cvt8(va0, va1);
    *(f16x8*)&sB[0][arow][akq]      = cvt8(vb00, vb01);
    *(f16x8*)&sB[0][64 + arow][akq] = cvt8(vb10, vb11);
    __syncthreads();
    int cur = 0;
    for (int kt = 0; kt < NT; ++kt) {
        if (kt + 1 < NT) {
            int ko = (kt + 1) * 32;
            va0  = *(const float4*)(pa + ko);  va1  = *(const float4*)(pa + ko + 4);
            vb00 = *(const float4*)(pb0 + ko); vb01 = *(const float4*)(pb0 + ko + 4);
            vb10 = *(const float4*)(pb1 + ko); vb11 = *(const float4*)(pb1 + ko + 4);
        }
        f16x8 ah[2], bh[4];
#pragma unroll
        for (int fi = 0; fi < 2; ++fi)
            ah[fi] = *(const f16x8*)&sA[cur][wr * 32 + fi * 16 + lc][lr * 8];
#pragma unroll
        for (int fj = 0; fj < 4; ++fj)
            bh[fj] = *(const f16x8*)&sB[cur][wc * 64 + fj * 16 + lc][lr * 8];
#pragma unroll
        for (int fi = 0; fi < 2; ++fi)
#pragma unroll
            for (int fj = 0; fj < 4; ++fj)
                acc[fi][fj] = mfma16(ah[fi], bh[fj], acc[fi][fj]);
        if (kt + 1 < NT) {
            *(f16x8*)&sA[cur ^ 1][arow][akq]      = cvt8(va0, va1);
            *(f16x8*)&sB[cur ^ 1][arow][akq]      = cvt8(vb00, vb01);
            *(f16x8*)&sB[cur ^ 1][64 + arow][akq] = cvt8(vb10, vb11);
            __syncthreads();
            cur ^= 1;
        }
    }
    // epilogue: relu -> xu f32, row-sum partials
    float rs[2][4] = {};
#pragma unroll
    for (int fi = 0; fi < 2; ++fi)
#pragma unroll
        for (int fj = 0; fj < 4; ++fj) {
            f32x4 d = acc[fi][fj];
#pragma unroll
            for (int r = 0; r < 4; ++r) {
                int i = i0 + wr * 32 + fi * 16 + lr * 4 + r;
                int j = j0 + wc * 64 + fj * 16 + lc;
                float vv = fmaxf(d[r], 0.f);
                xu[(size_t)i * NN + j] = vv;
                rs[fi][r] += vv;
            }
        }
#pragma unroll
    for (int fi = 0; fi < 2; ++fi)
#pragma unroll
        for (int r = 0; r < 4; ++r) {
            float v = rs[fi][r];
#pragma unroll
            for (int m = 1; m < 16; m <<= 1) v += __shfl_xor(v, m, 64);
            if (lc == 0) ssum[wr * 32 + fi * 16 + lr * 4 + r][wc] = v;
        }
    __syncthreads();
    if (t < 64) Spart[(size_t)blockIdx.x * ROWS + i0 + t] = ssum[t][0] + ssum[t][1];

    // fused LN^T(emb) for this M-tile's 64 rows (only one block per M-tile)
    if (blockIdx.x == 0) {
        const int b = i0 >> 8, tbase = i0 & 255;
        for (int half = 0; half < 2; ++half) {
            __syncthreads();
            for (int rr = 0; rr < 16; ++rr) {
                int tloc = wid * 16 + rr;
                const float* p = emb + (size_t)(i0 + tloc) * DD + lane * 4;
                float4 v = *(const float4*)p;
                float s  = v.x + v.y + v.z + v.w;
                float s2 = v.x*v.x + v.y*v.y + v.z*v.z + v.w*v.w;
#pragma unroll
                for (int o = 32; o; o >>= 1) {
                    s  += __shfl_xor(s,  o, 64);
                    s2 += __shfl_xor(s2, o, 64);
                }
                float m  = s * (1.0f / 256.0f);
                float sc = rsqrtf(s2 * (1.0f / 256.0f) - m * m + 1e-5f);
                if ((lane >> 5) == half) {
                    int jloc = (lane & 31) * 4;
                    sT[jloc + 0][tloc] = (f16)((v.x - m) * sc);
                    sT[jloc + 1][tloc] = (f16)((v.y - m) * sc);
                    sT[jloc + 2][tloc] = (f16)((v.z - m) * sc);
                    sT[jloc + 3][tloc] = (f16)((v.w - m) * sc);
                }
            }
            __syncthreads();
            int jl = t & 127, th = t >> 7;
            size_t o = ((size_t)b * DD + half * 128 + jl) * TT + tbase + th * 32;
#pragma unroll
            for (int q = 0; q < 4; ++q)
                *(f16x8*)(lnvTf + o + q * 8) = *(const f16x8*)&sT[jl][th * 32 + q * 8];
        }
    }
}

// ===== K2: x-scan with inline normalizer computation =======================
__launch_bounds__(256)
__global__ void k_xscan(const float* __restrict__ xu, const float* __restrict__ Spart,
                        f16* __restrict__ xf) {
    __shared__ float Gs[16][16], Hs[16][16], Cs[16][16];
    __shared__ float sS[256], sRC[256];
    __shared__ int bad;
    const int b = blockIdx.x >> 6, jgrp = blockIdx.x & 63;
    const int tid = threadIdx.x;
    float s = 0.f;
#pragma unroll
    for (int g = 0; g < 8; ++g) s += Spart[(size_t)g * ROWS + b * TT + tid];
    if (tid == 0) bad = 0;
    sS[tid] = s;
    __syncthreads();
    float us = (tid == 0) ? s : (0.97f + s);
    if (us < 1e-12f) bad = 1;
    __syncthreads();
    if (!bad) {
        sRC[tid] = 1.0f / us;
    } else if (tid == 0) {
        float sigma = 0.f;
        for (int tt = 0; tt < TT; ++tt) {
            float u2 = fmaf(0.97f, sigma, sS[tt]);
            float r  = 1.0f / fmaxf(u2, 1e-12f);
            sRC[tt] = r;
            sigma = u2 * r;
        }
    }
    __syncthreads();

    const int ck = tid >> 4, jl = tid & 15;
    const int j  = jgrp * 16 + jl;
    const size_t base = ((size_t)b * TT + ck * 16) * NN + j;
    float xur[16], rcr[16];
#pragma unroll
    for (int i = 0; i < 16; ++i) xur[i] = xu[base + (size_t)i * NN];
#pragma unroll
    for (int i = 0; i < 16; ++i) rcr[i] = sRC[ck * 16 + i];
    float xs = 0.f, G = 1.f;
#pragma unroll
    for (int i = 0; i < 16; ++i) {
        xs = fmaf(0.97f, xs, xur[i]) * rcr[i];
        G *= 0.97f * rcr[i];
    }
    Gs[ck][jl] = G;
    Hs[ck][jl] = xs;
    __syncthreads();
    if (tid < 16) {
        float cr = 0.f;
        Cs[0][tid] = 0.f;
#pragma unroll
        for (int cc = 0; cc < 15; ++cc) {
            cr = fmaf(Gs[cc][tid], cr, Hs[cc][tid]);
            Cs[cc + 1][tid] = cr;
        }
    }
    __syncthreads();
    xs = Cs[ck][jl];
#pragma unroll
    for (int i = 0; i < 16; ++i) {
        xs = fmaf(0.97f, xs, xur[i]) * rcr[i];
        xf[base + (size_t)i * NN] = (f16)xs;
    }
}

// ===== K3: W = causal-decay mask . (X X^T), 64x64 tile, batched ============
__launch_bounds__(256)
__global__ void k_W(const f16* __restrict__ xf, f16* __restrict__ Wf) {
    const int b = blockIdx.z;
    const f16* X = xf + (size_t)b * TT * NN;
    f16* Wb = Wf + (size_t)b * TT * TT;
    const int i0 = blockIdx.y * 64, j0 = blockIdx.x * 64;
    const int t = threadIdx.x, lane = t & 63, wid = t >> 6;
    const int wr = wid >> 1, wc = wid & 1;
    const int lr = lane >> 4, lc = lane & 15;
    const float L2D = -0.043943348f;  // log2(0.97)

    if (j0 > i0) {  // fully-masked tile
#pragma unroll
        for (int fi = 0; fi < 2; ++fi)
#pragma unroll
            for (int fj = 0; fj < 2; ++fj)
#pragma unroll
                for (int r = 0; r < 4; ++r) {
                    int i = i0 + wr * 32 + fi * 16 + lr * 4 + r;
                    int j = j0 + wc * 32 + fj * 16 + lc;
                    Wb[(size_t)i * TT + j] = (f16)0.f;
                }
        return;
    }

    __shared__ __align__(16) f16 sA[2][64][40], sB[2][64][40];
    const int srow = t >> 2, skq = (t & 3) * 8;
    f32x4 acc[2][2];
    const f32x4 z4 = {0.f, 0.f, 0.f, 0.f};
    acc[0][0] = z4; acc[0][1] = z4; acc[1][0] = z4; acc[1][1] = z4;

    const int NT = NN / 32;  // 32
    const f16* pa = X + (size_t)(i0 + srow) * NN + skq;
    const f16* pb = X + (size_t)(j0 + srow) * NN + skq;
    f16x8 va = *(const f16x8*)pa;
    f16x8 vb = *(const f16x8*)pb;
    *(f16x8*)&sA[0][srow][skq] = va;
    *(f16x8*)&sB[0][srow][skq] = vb;
    __syncthreads();
    int cur = 0;
    for (int kt = 0; kt < NT; ++kt) {
        if (kt + 1 < NT) {
            va = *(const f16x8*)(pa + (kt + 1) * 32);
            vb = *(const f16x8*)(pb + (kt + 1) * 32);
        }
        f16x8 ah0 = *(const f16x8*)&sA[cur][wr * 32 + lc][lr * 8];
        f16x8 ah1 = *(const f16x8*)&sA[cur][wr * 32 + 16 + lc][lr * 8];
        f16x8 bh0 = *(const f16x8*)&sB[cur][wc * 32 + lc][lr * 8];
        f16x8 bh1 = *(const f16x8*)&sB[cur][wc * 32 + 16 + lc][lr * 8];
        acc[0][0] = mfma16(ah0, bh0, acc[0][0]);
        acc[0][1] = mfma16(ah0, bh1, acc[0][1]);
        acc[1][0] = mfma16(ah1, bh0, acc[1][0]);
        acc[1][1] = mfma16(ah1, bh1, acc[1][1]);
        if (kt + 1 < NT) {
            *(f16x8*)&sA[cur ^ 1][srow][skq] = va;
            *(f16x8*)&sB[cur ^ 1][srow][skq] = vb;
            __syncthreads();
            cur ^= 1;
        }
    }
#pragma unroll
    for (int fi = 0; fi < 2; ++fi)
#pragma unroll
        for (int fj = 0; fj < 2; ++fj) {
            f32x4 d = acc[fi][fj];
#pragma unroll
            for (int r = 0; r < 4; ++r) {
                int i = i0 + wr * 32 + fi * 16 + lr * 4 + r;
                int j = j0 + wc * 32 + fj * 16 + lc;
                float w = 0.f;
                if (j < i) w = exp2f((float)(i - 1 - j) * L2D) * d[r];
                Wb[(size_t)i * TT + j] = (f16)w;
            }
        }
}

// ===== K4: a = W @ lnv, 64x64 tile, batched (both operands f16) ============
__launch_bounds__(256)
__global__ void k_ag(const f16* __restrict__ Wf, const f16* __restrict__ lnvTf,
                     float* __restrict__ a) {
    const int b = blockIdx.z;
    const f16* A = Wf + (size_t)b * TT * TT;
    const f16* B = lnvTf + (size_t)b * DD * TT;
    float* C = a + (size_t)b * TT * DD;
    const int i0 = blockIdx.y * 64, j0 = blockIdx.x * 64;
    const int t = threadIdx.x, lane = t & 63, wid = t >> 6;
    const int wr = wid >> 1, wc = wid & 1;
    const int lr = lane >> 4, lc = lane & 15;
    __shared__ __align__(16) f16 sA[2][64][40], sB[2][64][40];
    const int srow = t >> 2, skq = (t & 3) * 8;
    f32x4 acc[2][2];
    const f32x4 z4 = {0.f, 0.f, 0.f, 0.f};
    acc[0][0] = z4; acc[0][1] = z4; acc[1][0] = z4; acc[1][1] = z4;

    const int NT = TT / 32;  // 8
    const f16* pa = A + (size_t)(i0 + srow) * TT + skq;
    const f16* pb = B + (size_t)(j0 + srow) * TT + skq;
    f16x8 va = *(const f16x8*)pa;
    f16x8 vb = *(const f16x8*)pb;
    *(f16x8*)&sA[0][srow][skq] = va;
    *(f16x8*)&sB[0][srow][skq] = vb;
    __syncthreads();
    int cur = 0;
    for (int kt = 0; kt < NT; ++kt) {
        if (kt + 1 < NT) {
            va = *(const f16x8*)(pa + (kt + 1) * 32);
            vb = *(const f16x8*)(pb + (kt + 1) * 32);
        }
        f16x8 ah0 = *(const f16x8*)&sA[cur][wr * 32 + lc][lr * 8];
        f16x8 ah1 = *(const f16x8*)&sA[cur][wr * 32 + 16 + lc][lr * 8];
        f16x8 bh0 = *(const f16x8*)&sB[cur][wc * 32 + lc][lr * 8];
        f16x8 bh1 = *(const f16x8*)&sB[cur][wc * 32 + 16 + lc][lr * 8];
        acc[0][0] = mfma16(ah0, bh0, acc[0][0]);
        acc[0][1] = mfma16(ah0, bh1, acc[0][1]);
        acc[1][0] = mfma16(ah1, bh0, acc[1][0]);
        acc[1][1] = mfma16(ah1, bh1, acc[1][1]);
        if (kt + 1 < NT) {
            *(f16x8*)&sA[cur ^ 1][srow][skq] = va;
            *(f16x8*)&sB[cur ^ 1][srow][skq] = vb;
            __syncthreads();
            cur ^= 1;
        }
    }
#pragma unroll
    for (int fi = 0; fi < 2; ++fi)
#pragma unroll
        for (int fj = 0; fj < 2; ++fj) {
            f32x4 d = acc[fi][fj];
#pragma unroll
            for (int r = 0; r < 4; ++r) {
                int i = i0 + wr * 32 + fi * 16 + lr * 4 + r;
                int j = j0 + wc * 32 + fj * 16 + lc;
                C[(size_t)i * DD + j] = d[r];
            }
        }
}

// ===== LN rows of 256: MODE 1: f16 out.  MODE 2: f32 out of LN(in+in2) =====
template <int MODE>
__launch_bounds__(256)
__global__ void ln_kernel(const float* __restrict__ in, const float* __restrict__ in2,
                          float* __restrict__ outf, f16* __restrict__ outh) {
    int wave = threadIdx.x >> 6;
    int lane = threadIdx.x & 63;
    int row  = blockIdx.x * 4 + wave;
    const float* p = in + (size_t)row * DD;
    float4 v = *(const float4*)(p + lane * 4);
    if (MODE == 2) {
        float4 w = *(const float4*)(in2 + (size_t)row * DD + lane * 4);
        v.x += w.x; v.y += w.y; v.z += w.z; v.w += w.w;
    }
    float s  = v.x + v.y + v.z + v.w;
    float s2 = v.x*v.x + v.y*v.y + v.z*v.z + v.w*v.w;
#pragma unroll
    for (int o = 32; o; o >>= 1) {
        s  += __shfl_xor(s,  o, 64);
        s2 += __shfl_xor(s2, o, 64);
    }
    float m   = s * (1.0f / 256.0f);
    float var = s2 * (1.0f / 256.0f) - m * m;
    float sc  = rsqrtf(var + 1e-5f);
    float r4[4] = {(v.x - m) * sc, (v.y - m) * sc, (v.z - m) * sc, (v.w - m) * sc};
    if (MODE == 1) {
        f16x4 h = {(f16)r4[0], (f16)r4[1], (f16)r4[2], (f16)r4[3]};
        *(f16x4*)(outh + (size_t)row * DD + lane * 4) = h;
    } else {
        float4 o4 = {r4[0], r4[1], r4[2], r4[3]};
        *(float4*)(outf + (size_t)row * DD + lane * 4) = o4;
    }
}

// ===== K6: y = relu(aln @ Dy^T) * x, 64x128 tile, Dy f32 on-the-fly ========
__launch_bounds__(256)
__global__ void k_y(const f16* __restrict__ alnf, const float* __restrict__ Dy,
                    f16* __restrict__ yf, const f16* __restrict__ xf) {
    const int i0 = blockIdx.y * 64, j0 = blockIdx.x * 128;
    const int t = threadIdx.x, lane = t & 63, wid = t >> 6;
    const int wr = wid >> 1, wc = wid & 1;
    const int lr = lane >> 4, lc = lane & 15;
    __shared__ __align__(16) f16 sA[2][64][40], sB[2][128][40];
    const int arow = t >> 2, akq = (t & 3) * 8;
    f32x4 acc[2][4];
    const f32x4 z4 = {0.f, 0.f, 0.f, 0.f};
#pragma unroll
    for (int fi = 0; fi < 2; ++fi)
#pragma unroll
        for (int fj = 0; fj < 4; ++fj) acc[fi][fj] = z4;

    const int NT = DD / 32;  // 8
    const f16*   pa  = alnf + (size_t)(i0 + arow) * DD + akq;
    const float* pb0 = Dy + (size_t)(j0 + arow) * DD + akq;
    const float* pb1 = Dy + (size_t)(j0 + 64 + arow) * DD + akq;
    f16x8  va   = *(const f16x8*)pa;
    float4 vb00 = *(const float4*)pb0, vb01 = *(const float4*)(pb0 + 4);
    float4 vb10 = *(const float4*)pb1, vb11 = *(const float4*)(pb1 + 4);
    *(f16x8*)&sA[0][arow][akq]      = va;
    *(f16x8*)&sB[0][arow][akq]      = cvt8(vb00, vb01);
    *(f16x8*)&sB[0][64 + arow][akq] = cvt8(vb10, vb11);
    __syncthreads();
    int cur = 0;
    for (int kt = 0; kt < NT; ++kt) {
        if (kt + 1 < NT) {
            int ko = (kt + 1) * 32;
            va   = *(const f16x8*)(pa + ko);
            vb00 = *(const float4*)(pb0 + ko); vb01 = *(const float4*)(pb0 + ko + 4);
            vb10 = *(const float4*)(pb1 + ko); vb11 = *(const float4*)(pb1 + ko + 4);
        }
        f16x8 ah[2], bh[4];
#pragma unroll
        for (int fi = 0; fi < 2; ++fi)
            ah[fi] = *(const f16x8*)&sA[cur][wr * 32 + fi * 16 + lc][lr * 8];
#pragma unroll
        for (int fj = 0; fj < 4; ++fj)
            bh[fj] = *(const f16x8*)&sB[cur][wc * 64 + fj * 16 + lc][lr * 8];
#pragma unroll
        for (int fi = 0; fi < 2; ++fi)
#pragma unroll
            for (int fj = 0; fj < 4; ++fj)
                acc[fi][fj] = mfma16(ah[fi], bh[fj], acc[fi][fj]);
        if (kt + 1 < NT) {
            *(f16x8*)&sA[cur ^ 1][arow][akq]      = va;
            *(f16x8*)&sB[cur ^ 1][arow][akq]      = cvt8(vb00, vb01);
            *(f16x8*)&sB[cur ^ 1][64 + arow][akq] = cvt8(vb10, vb11);
            __syncthreads();
            cur ^= 1;
        }
    }
#pragma unroll
    for (int fi = 0; fi < 2; ++fi)
#pragma unroll
        for (int fj = 0; fj < 4; ++fj) {
            f32x4 d = acc[fi][fj];
#pragma unroll
            for (int r = 0; r < 4; ++r) {
                int i = i0 + wr * 32 + fi * 16 + lr * 4 + r;
                int j = j0 + wc * 64 + fj * 16 + lc;
                size_t o = (size_t)i * NN + j;
                float vv = fmaxf(d[r], 0.f) * (float)xf[o];
                yf[o] = (f16)vv;
            }
        }
}

// ===== K7: vpart[z] = y @ E^T (K-half z), 64x64 tile, E f32 on-the-fly =====
__launch_bounds__(256)
__global__ void k_vg(const f16* __restrict__ yf, const float* __restrict__ E,
                     float* __restrict__ vpart) {
    const int z = blockIdx.z;
    float* C = vpart + (size_t)z * ROWS * DD;
    const int i0 = blockIdx.y * 64, j0 = blockIdx.x * 64;
    const int t = threadIdx.x, lane = t & 63, wid = t >> 6;
    const int wr = wid >> 1, wc = wid & 1;
    const int lr = lane >> 4, lc = lane & 15;
    __shared__ __align__(16) f16 sA[2][64][40], sB[2][64][40];
    const int srow = t >> 2, skq = (t & 3) * 8;
    f32x4 acc[2][2];
    const f32x4 z4 = {0.f, 0.f, 0.f, 0.f};
    acc[0][0] = z4; acc[0][1] = z4; acc[1][0] = z4; acc[1][1] = z4;

    const int NT = 512 / 32;  // 16
    const f16*   pa = yf + (size_t)(i0 + srow) * NN + z * 512 + skq;
    const float* pb = E  + (size_t)(j0 + srow) * NN + z * 512 + skq;
    f16x8  va  = *(const f16x8*)pa;
    float4 vb0 = *(const float4*)pb, vb1 = *(const float4*)(pb + 4);
    *(f16x8*)&sA[0][srow][skq] = va;
    *(f16x8*)&sB[0][srow][skq] = cvt8(vb0, vb1);
    __syncthreads();
    int cur = 0;
    for (int kt = 0; kt < NT; ++kt) {
        if (kt + 1 < NT) {
            int ko = (kt + 1) * 32;
            va  = *(const f16x8*)(pa + ko);
            vb0 = *(const float4*)(pb + ko); vb1 = *(const float4*)(pb + ko + 4);
        }
        f16x8 ah0 = *(const f16x8*)&sA[cur][wr * 32 + lc][lr * 8];
        f16x8 ah1 = *(const f16x8*)&sA[cur][wr * 32 + 16 + lc][lr * 8];
        f16x8 bh0 = *(const f16x8*)&sB[cur][wc * 32 + lc][lr * 8];
        f16x8 bh1 = *(const f16x8*)&sB[cur][wc * 32 + 16 + lc][lr * 8];
        acc[0][0] = mfma16(ah0, bh0, acc[0][0]);
        acc[0][1] = mfma16(ah0, bh1, acc[0][1]);
        acc[1][0] = mfma16(ah1, bh0, acc[1][0]);
        acc[1][1] = mfma16(ah1, bh1, acc[1][1]);
        if (kt + 1 < NT) {
            *(f16x8*)&sA[cur ^ 1][srow][skq] = va;
            *(f16x8*)&sB[cur ^ 1][srow][skq] = cvt8(vb0, vb1);
            __syncthreads();
            cur ^= 1;
        }
    }
#pragma unroll
    for (int fi = 0; fi < 2; ++fi)
#pragma unroll
        for (int fj = 0; fj < 2; ++fj) {
            f32x4 d = acc[fi][fj];
#pragma unroll
            for (int r = 0; r < 4; ++r) {
                int i = i0 + wr * 32 + fi * 16 + lr * 4 + r;
                int j = j0 + wc * 32 + fj * 16 + lc;
                C[(size_t)i * DD + j] = d[r];
            }
        }
}

extern "C" void kernel_launch(void* const* d_in, const int* in_sizes, int n_in,
                              void* d_out, int out_size, void* d_ws, size_t ws_size,
                              hipStream_t stream) {
    (void)in_sizes; (void)n_in; (void)out_size; (void)ws_size;
    const float* emb = (const float*)d_in[0];   // (B,T,d)
    const float* E   = (const float*)d_in[1];   // (d,n)
    const float* Dx  = (const float*)d_in[2];   // (n,d)
    const float* Dy  = (const float*)d_in[3];   // (n,d)
    float* out = (float*)d_out;                 // (B,T,d)

    char* wsb = (char*)d_ws;
    f16*   lnvTf = (f16*)(wsb + 0);           // 1 MB   [b][j][t]
    f16*   xf    = (f16*)(wsb + 1048576);     // 4 MB   [b*t][n]
    f16*   Wf    = (f16*)(wsb + 5242880);     // 1 MB   [b][t][s]
    f16*   alnf  = (f16*)(wsb + 6291456);     // 1 MB
    f16*   yf    = (f16*)(wsb + 7340032);     // 4 MB
    float* xu    = (float*)(wsb + 11534336);  // 8 MB
    float* a     = (float*)(wsb + 19922944);  // 2 MB
    float* vpart = (float*)(wsb + 22020096);  // 4 MB (2 x ROWS*DD)
    float* Spart = (float*)(wsb + 26214400);  // 64 KB (8 x ROWS)

    // K1: xu GEMM + rowsum partials + fused LN^T(emb)
    k_xu<<<dim3(NN / 128, ROWS / 64), 256, 0, stream>>>(emb, Dx, xu, Spart, lnvTf);
    // K2: x scan (inline normalizer)
    k_xscan<<<BB * (NN / 16), 256, 0, stream>>>(xu, Spart, xf);
    // K3: W = mask . (X X^T)
    k_W<<<dim3(TT / 64, TT / 64, BB), 256, 0, stream>>>(xf, Wf);
    // K4: a = W @ lnv
    k_ag<<<dim3(DD / 64, TT / 64, BB), 256, 0, stream>>>(Wf, lnvTf, a);
    // K5: aln = LN(a) -> f16
    ln_kernel<1><<<ROWS / 4, 256, 0, stream>>>(a, nullptr, nullptr, alnf);
    // K6: y = relu(aln @ Dy^T) * x
    k_y<<<dim3(NN / 128, ROWS / 64), 256, 0, stream>>>(alnf, Dy, yf, xf);
    // K7: vpart = y @ E^T split-K=2
    k_vg<<<dim3(DD / 64, ROWS / 64, 2), 256, 0, stream>>>(yf, E, vpart);
    // K8: out = LN(vpart0 + vpart1)
    ln_kernel<2><<<ROWS / 4, 256, 0, stream>>>(
        vpart, vpart + (size_t)ROWS * DD, out, nullptr);
}

// Round 11
// 60.668 us; speedup vs baseline: 1.7263x; 1.3241x over previous
//
#include <hip/hip_runtime.h>
#include <math.h>

// BDH recurrence, 8-kernel pipeline; fp16 MFMA GEMMs (f32 accum), all GEMM
// operands pre-converted to f16 (round-8 measured-best arrangement).
//  K1 cvt(emb,E,Dx,Dy)->f16 + LN^T(emb)->f16                      1408
//  K2 xu = relu(emb @ Dx^T) -> f16 + rowsum partials              (8,32)
//  K3 x-scan (inline normalizer, exact fallback)                  512
//  K4 W = causal-decay mask . (X X^T)  batched                    (4,4,8)
//  K5 aln = LN(W @ lnv), 16-row blocks (grid 128)                 (16,8)
//  K6 y = relu(aln @ Dy^T) * x                                    (8,32)
//  K7 vpart = y @ E^T  split-K=2                                  (4,32,2)
//  K8 out = LN(vpart0+vpart1)                                     512

#define TT 256
#define BB 8
#define DD 256
#define NN 1024
#define ROWS (BB*TT)   // 2048

using f16   = _Float16;
using f16x4 = __attribute__((ext_vector_type(4))) _Float16;
using f16x8 = __attribute__((ext_vector_type(8))) _Float16;
using f32x4 = __attribute__((ext_vector_type(4))) float;

__device__ inline f32x4 mfma16(f16x8 a, f16x8 b, f32x4 c) {
    return __builtin_amdgcn_mfma_f32_16x16x32_f16(a, b, c, 0, 0, 0);
}

// ===== K1: convert inputs to fp16 + LN-transpose of emb ====================
__launch_bounds__(256)
__global__ void cvtln_kernel(const float* __restrict__ emb, const float* __restrict__ E,
                             const float* __restrict__ Dx, const float* __restrict__ Dy,
                             f16* __restrict__ embf, f16* __restrict__ Ef,
                             f16* __restrict__ Dxf, f16* __restrict__ Dyf,
                             f16* __restrict__ lnvTf) {
    __shared__ f16 sT[256][24];
    if (blockIdx.x < 1280) {
        int base = (blockIdx.x * 256 + threadIdx.x) * 4;
        const float* s; f16* d; int loc;
        if      (base <  524288) { s = emb; d = embf; loc = base; }
        else if (base <  786432) { s = E;   d = Ef;   loc = base - 524288; }
        else if (base < 1048576) { s = Dx;  d = Dxf;  loc = base - 786432; }
        else                     { s = Dy;  d = Dyf;  loc = base - 1048576; }
        float4 v = *(const float4*)(s + loc);
        f16x4 h = {(f16)v.x, (f16)v.y, (f16)v.z, (f16)v.w};
        *(f16x4*)(d + loc) = h;
        return;
    }
    const int bx = blockIdx.x - 1280;
    const int b  = bx >> 4;
    const int t0 = (bx & 15) * 16;
    const int wave = threadIdx.x >> 6;
    const int lane = threadIdx.x & 63;
#pragma unroll
    for (int rr = 0; rr < 4; ++rr) {
        int tloc = wave * 4 + rr;
        const float* p = emb + ((size_t)b * TT + t0 + tloc) * DD;
        float4 v = *(const float4*)(p + lane * 4);
        float s  = v.x + v.y + v.z + v.w;
        float s2 = v.x*v.x + v.y*v.y + v.z*v.z + v.w*v.w;
#pragma unroll
        for (int o = 32; o; o >>= 1) {
            s  += __shfl_xor(s,  o, 64);
            s2 += __shfl_xor(s2, o, 64);
        }
        float m   = s * (1.0f / 256.0f);
        float sc  = rsqrtf(s2 * (1.0f / 256.0f) - m * m + 1e-5f);
        sT[lane * 4 + 0][tloc] = (f16)((v.x - m) * sc);
        sT[lane * 4 + 1][tloc] = (f16)((v.y - m) * sc);
        sT[lane * 4 + 2][tloc] = (f16)((v.z - m) * sc);
        sT[lane * 4 + 3][tloc] = (f16)((v.w - m) * sc);
    }
    __syncthreads();
    int j = threadIdx.x;
    size_t o = ((size_t)b * DD + j) * TT + t0;
    *(f16x8*)(lnvTf + o)     = *(const f16x8*)&sT[j][0];
    *(f16x8*)(lnvTf + o + 8) = *(const f16x8*)&sT[j][8];
}

// ===== K2: xu = relu(emb @ Dx^T) -> f16, 64x128 tile, + Spart ==============
__launch_bounds__(256)
__global__ void k_xu(const f16* __restrict__ A, const f16* __restrict__ B,
                     f16* __restrict__ xuh, float* __restrict__ Spart) {
    const int i0 = blockIdx.y * 64, j0 = blockIdx.x * 128;
    const int t = threadIdx.x, lane = t & 63, wid = t >> 6;
    const int wr = wid >> 1, wc = wid & 1;
    const int lr = lane >> 4, lc = lane & 15;
    __shared__ __align__(16) f16 sA[2][64][40], sB[2][128][40];
    __shared__ float ssum[64][2];
    const int arow = t >> 2, akq = (t & 3) * 8;
    f32x4 acc[2][4];
    const f32x4 z4 = {0.f, 0.f, 0.f, 0.f};
#pragma unroll
    for (int fi = 0; fi < 2; ++fi)
#pragma unroll
        for (int fj = 0; fj < 4; ++fj) acc[fi][fj] = z4;

    const int NT = DD / 32;  // 8
    const f16* pa  = A + (size_t)(i0 + arow) * DD + akq;
    const f16* pb0 = B + (size_t)(j0 + arow) * DD + akq;
    const f16* pb1 = B + (size_t)(j0 + 64 + arow) * DD + akq;
    f16x8 va  = *(const f16x8*)pa;
    f16x8 vb0 = *(const f16x8*)pb0;
    f16x8 vb1 = *(const f16x8*)pb1;
    *(f16x8*)&sA[0][arow][akq]      = va;
    *(f16x8*)&sB[0][arow][akq]      = vb0;
    *(f16x8*)&sB[0][64 + arow][akq] = vb1;
    __syncthreads();
    int cur = 0;
    for (int kt = 0; kt < NT; ++kt) {
        if (kt + 1 < NT) {
            int ko = (kt + 1) * 32;
            va  = *(const f16x8*)(pa + ko);
            vb0 = *(const f16x8*)(pb0 + ko);
            vb1 = *(const f16x8*)(pb1 + ko);
        }
        f16x8 ah[2], bh[4];
#pragma unroll
        for (int fi = 0; fi < 2; ++fi)
            ah[fi] = *(const f16x8*)&sA[cur][wr * 32 + fi * 16 + lc][lr * 8];
#pragma unroll
        for (int fj = 0; fj < 4; ++fj)
            bh[fj] = *(const f16x8*)&sB[cur][wc * 64 + fj * 16 + lc][lr * 8];
#pragma unroll
        for (int fi = 0; fi < 2; ++fi)
#pragma unroll
            for (int fj = 0; fj < 4; ++fj)
                acc[fi][fj] = mfma16(ah[fi], bh[fj], acc[fi][fj]);
        if (kt + 1 < NT) {
            *(f16x8*)&sA[cur ^ 1][arow][akq]      = va;
            *(f16x8*)&sB[cur ^ 1][arow][akq]      = vb0;
            *(f16x8*)&sB[cur ^ 1][64 + arow][akq] = vb1;
            __syncthreads();
            cur ^= 1;
        }
    }
    float rs[2][4] = {};
#pragma unroll
    for (int fi = 0; fi < 2; ++fi)
#pragma unroll
        for (int fj = 0; fj < 4; ++fj) {
            f32x4 d = acc[fi][fj];
#pragma unroll
            for (int r = 0; r < 4; ++r) {
                int i = i0 + wr * 32 + fi * 16 + lr * 4 + r;
                int j = j0 + wc * 64 + fj * 16 + lc;
                float vv = fmaxf(d[r], 0.f);
                xuh[(size_t)i * NN + j] = (f16)vv;
                rs[fi][r] += vv;
            }
        }
#pragma unroll
    for (int fi = 0; fi < 2; ++fi)
#pragma unroll
        for (int r = 0; r < 4; ++r) {
            float v = rs[fi][r];
#pragma unroll
            for (int m = 1; m < 16; m <<= 1) v += __shfl_xor(v, m, 64);
            if (lc == 0) ssum[wr * 32 + fi * 16 + lr * 4 + r][wc] = v;
        }
    __syncthreads();
    if (t < 64) Spart[(size_t)blockIdx.x * ROWS + i0 + t] = ssum[t][0] + ssum[t][1];
}

// ===== K3: x-scan with inline normalizer ===================================
__launch_bounds__(256)
__global__ void k_xscan(const f16* __restrict__ xuh, const float* __restrict__ Spart,
                        f16* __restrict__ xf) {
    __shared__ float Gs[16][16], Hs[16][16], Cs[16][16];
    __shared__ float sS[256], sRC[256];
    __shared__ int bad;
    const int b = blockIdx.x >> 6, jgrp = blockIdx.x & 63;
    const int tid = threadIdx.x;
    float s = 0.f;
#pragma unroll
    for (int g = 0; g < 8; ++g) s += Spart[(size_t)g * ROWS + b * TT + tid];
    if (tid == 0) bad = 0;
    sS[tid] = s;
    __syncthreads();
    float us = (tid == 0) ? s : (0.97f + s);
    if (us < 1e-12f) bad = 1;
    __syncthreads();
    if (!bad) {
        sRC[tid] = 1.0f / us;
    } else if (tid == 0) {
        float sigma = 0.f;
        for (int tt = 0; tt < TT; ++tt) {
            float u2 = fmaf(0.97f, sigma, sS[tt]);
            float r  = 1.0f / fmaxf(u2, 1e-12f);
            sRC[tt] = r;
            sigma = u2 * r;
        }
    }
    __syncthreads();

    const int ck = tid >> 4, jl = tid & 15;
    const int j  = jgrp * 16 + jl;
    const size_t base = ((size_t)b * TT + ck * 16) * NN + j;
    float xur[16], rcr[16];
#pragma unroll
    for (int i = 0; i < 16; ++i) xur[i] = (float)xuh[base + (size_t)i * NN];
#pragma unroll
    for (int i = 0; i < 16; ++i) rcr[i] = sRC[ck * 16 + i];
    float xs = 0.f, G = 1.f;
#pragma unroll
    for (int i = 0; i < 16; ++i) {
        xs = fmaf(0.97f, xs, xur[i]) * rcr[i];
        G *= 0.97f * rcr[i];
    }
    Gs[ck][jl] = G;
    Hs[ck][jl] = xs;
    __syncthreads();
    if (tid < 16) {
        float cr = 0.f;
        Cs[0][tid] = 0.f;
#pragma unroll
        for (int cc = 0; cc < 15; ++cc) {
            cr = fmaf(Gs[cc][tid], cr, Hs[cc][tid]);
            Cs[cc + 1][tid] = cr;
        }
    }
    __syncthreads();
    xs = Cs[ck][jl];
#pragma unroll
    for (int i = 0; i < 16; ++i) {
        xs = fmaf(0.97f, xs, xur[i]) * rcr[i];
        xf[base + (size_t)i * NN] = (f16)xs;
    }
}

// ===== generic f16 64x64 NT GEMM (round-8 measured), EPI 0 f32 / 3 mask ====
template <int EPI>
__launch_bounds__(256)
__global__ void g64_kernel(const f16* __restrict__ A, const f16* __restrict__ B,
                           float* __restrict__ Cf, f16* __restrict__ Ch,
                           int N, int ld, int Kloop,
                           long long sA_, long long sB_, long long sC_) {
    const int z = blockIdx.z;
    A += (size_t)z * sA_; B += (size_t)z * sB_;
    if (EPI == 0) Cf += (size_t)z * sC_; else Ch += (size_t)z * sC_;
    const int i0 = blockIdx.y * 64, j0 = blockIdx.x * 64;
    const int t = threadIdx.x, lane = t & 63, wid = t >> 6;
    const int wr = wid >> 1, wc = wid & 1;
    const int lr = lane >> 4, lc = lane & 15;
    const float L2D = -0.043943348f;  // log2(0.97)

    if (EPI == 3 && j0 > i0) {
#pragma unroll
        for (int fi = 0; fi < 2; ++fi)
#pragma unroll
            for (int fj = 0; fj < 2; ++fj)
#pragma unroll
                for (int r = 0; r < 4; ++r) {
                    int i = i0 + wr * 32 + fi * 16 + lr * 4 + r;
                    int j = j0 + wc * 32 + fj * 16 + lc;
                    Ch[(size_t)i * N + j] = (f16)0.f;
                }
        return;
    }

    __shared__ __align__(16) f16 sA[2][64][40], sB[2][64][40];
    const int srow = t >> 2, skq = (t & 3) * 8;
    f32x4 acc[2][2];
    const f32x4 z4 = {0.f, 0.f, 0.f, 0.f};
    acc[0][0] = z4; acc[0][1] = z4; acc[1][0] = z4; acc[1][1] = z4;

    const int NT = Kloop / 32;
    const f16* pa = A + (size_t)(i0 + srow) * ld + skq;
    const f16* pb = B + (size_t)(j0 + srow) * ld + skq;
    f16x8 va = *(const f16x8*)pa;
    f16x8 vb = *(const f16x8*)pb;
    *(f16x8*)&sA[0][srow][skq] = va;
    *(f16x8*)&sB[0][srow][skq] = vb;
    __syncthreads();
    int cur = 0;
    for (int kt = 0; kt < NT; ++kt) {
        if (kt + 1 < NT) {
            va = *(const f16x8*)(pa + (kt + 1) * 32);
            vb = *(const f16x8*)(pb + (kt + 1) * 32);
        }
        f16x8 ah0 = *(const f16x8*)&sA[cur][wr * 32 + lc][lr * 8];
        f16x8 ah1 = *(const f16x8*)&sA[cur][wr * 32 + 16 + lc][lr * 8];
        f16x8 bh0 = *(const f16x8*)&sB[cur][wc * 32 + lc][lr * 8];
        f16x8 bh1 = *(const f16x8*)&sB[cur][wc * 32 + 16 + lc][lr * 8];
        acc[0][0] = mfma16(ah0, bh0, acc[0][0]);
        acc[0][1] = mfma16(ah0, bh1, acc[0][1]);
        acc[1][0] = mfma16(ah1, bh0, acc[1][0]);
        acc[1][1] = mfma16(ah1, bh1, acc[1][1]);
        if (kt + 1 < NT) {
            *(f16x8*)&sA[cur ^ 1][srow][skq] = va;
            *(f16x8*)&sB[cur ^ 1][srow][skq] = vb;
            __syncthreads();
            cur ^= 1;
        }
    }
#pragma unroll
    for (int fi = 0; fi < 2; ++fi)
#pragma unroll
        for (int fj = 0; fj < 2; ++fj) {
            f32x4 d = acc[fi][fj];
#pragma unroll
            for (int r = 0; r < 4; ++r) {
                int i = i0 + wr * 32 + fi * 16 + lr * 4 + r;
                int j = j0 + wc * 32 + fj * 16 + lc;
                size_t o = (size_t)i * N + j;
                if (EPI == 0) {
                    Cf[o] = d[r];
                } else {
                    float w = 0.f;
                    if (j < i) w = exp2f((float)(i - 1 - j) * L2D) * d[r];
                    Ch[o] = (f16)w;
                }
            }
        }
}

// ===== K5: aln = LN(W @ lnv), 16-row blocks (grid 16x8 = 128) ==============
// Wave w owns 16 rows x cols [w*64, w*64+64): 4 frags; 5 ds_read : 4 MFMA.
__launch_bounds__(256)
__global__ void k_aln(const f16* __restrict__ Wf, const f16* __restrict__ lnvTf,
                      f16* __restrict__ alnf) {
    const int b = blockIdx.y;
    const int i0 = blockIdx.x * 16;
    const f16* A = Wf + (size_t)b * TT * TT;     // [256][256]
    const f16* B = lnvTf + (size_t)b * DD * TT;  // [256 j][256 t]
    const int t = threadIdx.x, lane = t & 63, w = t >> 6;
    const int lr = lane >> 4, lc = lane & 15;
    __shared__ __align__(16) f16 sA[2][16][40], sB[2][256][40];
    __shared__ float sS[4][16], sS2[4][16];
    const int arow = t >> 2, akq = (t & 3) * 8;   // A: threads 0..63
    const int brow = t >> 2, bkq = (t & 3) * 8;   // B: +q*64 rows
    f32x4 acc[4];
    const f32x4 z4 = {0.f, 0.f, 0.f, 0.f};
#pragma unroll
    for (int f = 0; f < 4; ++f) acc[f] = z4;

    const int NT = TT / 32;  // 8
    const f16* pa = A + (size_t)(i0 + arow) * TT + akq;
    const f16* pb = B + (size_t)brow * TT + bkq;
    f16x8 va;
    f16x8 vb[4];
    if (t < 64) va = *(const f16x8*)pa;
#pragma unroll
    for (int q = 0; q < 4; ++q)
        vb[q] = *(const f16x8*)(pb + (size_t)q * 64 * TT);
    if (t < 64) *(f16x8*)&sA[0][arow][akq] = va;
#pragma unroll
    for (int q = 0; q < 4; ++q)
        *(f16x8*)&sB[0][q * 64 + brow][bkq] = vb[q];
    __syncthreads();
    int cur = 0;
    for (int kt = 0; kt < NT; ++kt) {
        if (kt + 1 < NT) {
            int ko = (kt + 1) * 32;
            if (t < 64) va = *(const f16x8*)(pa + ko);
#pragma unroll
            for (int q = 0; q < 4; ++q)
                vb[q] = *(const f16x8*)(pb + (size_t)q * 64 * TT + ko);
        }
        f16x8 af = *(const f16x8*)&sA[cur][lc][lr * 8];
#pragma unroll
        for (int f = 0; f < 4; ++f) {
            f16x8 bf = *(const f16x8*)&sB[cur][w * 64 + f * 16 + lc][lr * 8];
            acc[f] = mfma16(af, bf, acc[f]);
        }
        if (kt + 1 < NT) {
            if (t < 64) *(f16x8*)&sA[cur ^ 1][arow][akq] = va;
#pragma unroll
            for (int q = 0; q < 4; ++q)
                *(f16x8*)&sB[cur ^ 1][q * 64 + brow][bkq] = vb[q];
            __syncthreads();
            cur ^= 1;
        }
    }
    // row LN across the 4 waves (each holds a 64-col quarter of each row)
    float s[4] = {}, s2[4] = {};
#pragma unroll
    for (int f = 0; f < 4; ++f)
#pragma unroll
        for (int r = 0; r < 4; ++r) { float v = acc[f][r]; s[r] += v; s2[r] += v * v; }
#pragma unroll
    for (int m = 1; m < 16; m <<= 1)
#pragma unroll
        for (int r = 0; r < 4; ++r) {
            s[r]  += __shfl_xor(s[r],  m, 64);
            s2[r] += __shfl_xor(s2[r], m, 64);
        }
    if (lc == 0)
#pragma unroll
        for (int r = 0; r < 4; ++r) { sS[w][lr * 4 + r] = s[r]; sS2[w][lr * 4 + r] = s2[r]; }
    __syncthreads();
    float mean[4], rstd[4];
#pragma unroll
    for (int r = 0; r < 4; ++r) {
        int row = lr * 4 + r;
        float tot  = sS[0][row] + sS[1][row] + sS[2][row] + sS[3][row];
        float tot2 = sS2[0][row] + sS2[1][row] + sS2[2][row] + sS2[3][row];
        mean[r] = tot * (1.f / 256.f);
        rstd[r] = rsqrtf(tot2 * (1.f / 256.f) - mean[r] * mean[r] + 1e-5f);
    }
#pragma unroll
    for (int f = 0; f < 4; ++f)
#pragma unroll
        for (int r = 0; r < 4; ++r) {
            int i = i0 + lr * 4 + r;
            int j = w * 64 + f * 16 + lc;
            alnf[((size_t)b * TT + i) * DD + j] = (f16)((acc[f][r] - mean[r]) * rstd[r]);
        }
}

// ===== K6: y = relu(aln @ Dy^T) * x, 64x128 tile, all f16 ==================
__launch_bounds__(256)
__global__ void k_y(const f16* __restrict__ A, const f16* __restrict__ B,
                    f16* __restrict__ yf, const f16* __restrict__ xf) {
    const int i0 = blockIdx.y * 64, j0 = blockIdx.x * 128;
    const int t = threadIdx.x, lane = t & 63, wid = t >> 6;
    const int wr = wid >> 1, wc = wid & 1;
    const int lr = lane >> 4, lc = lane & 15;
    __shared__ __align__(16) f16 sA[2][64][40], sB[2][128][40];
    const int arow = t >> 2, akq = (t & 3) * 8;
    f32x4 acc[2][4];
    const f32x4 z4 = {0.f, 0.f, 0.f, 0.f};
#pragma unroll
    for (int fi = 0; fi < 2; ++fi)
#pragma unroll
        for (int fj = 0; fj < 4; ++fj) acc[fi][fj] = z4;

    const int NT = DD / 32;  // 8
    const f16* pa  = A + (size_t)(i0 + arow) * DD + akq;
    const f16* pb0 = B + (size_t)(j0 + arow) * DD + akq;
    const f16* pb1 = B + (size_t)(j0 + 64 + arow) * DD + akq;
    f16x8 va  = *(const f16x8*)pa;
    f16x8 vb0 = *(const f16x8*)pb0;
    f16x8 vb1 = *(const f16x8*)pb1;
    *(f16x8*)&sA[0][arow][akq]      = va;
    *(f16x8*)&sB[0][arow][akq]      = vb0;
    *(f16x8*)&sB[0][64 + arow][akq] = vb1;
    __syncthreads();
    int cur = 0;
    for (int kt = 0; kt < NT; ++kt) {
        if (kt + 1 < NT) {
            int ko = (kt + 1) * 32;
            va  = *(const f16x8*)(pa + ko);
            vb0 = *(const f16x8*)(pb0 + ko);
            vb1 = *(const f16x8*)(pb1 + ko);
        }
        f16x8 ah[2], bh[4];
#pragma unroll
        for (int fi = 0; fi < 2; ++fi)
            ah[fi] = *(const f16x8*)&sA[cur][wr * 32 + fi * 16 + lc][lr * 8];
#pragma unroll
        for (int fj = 0; fj < 4; ++fj)
            bh[fj] = *(const f16x8*)&sB[cur][wc * 64 + fj * 16 + lc][lr * 8];
#pragma unroll
        for (int fi = 0; fi < 2; ++fi)
#pragma unroll
            for (int fj = 0; fj < 4; ++fj)
                acc[fi][fj] = mfma16(ah[fi], bh[fj], acc[fi][fj]);
        if (kt + 1 < NT) {
            *(f16x8*)&sA[cur ^ 1][arow][akq]      = va;
            *(f16x8*)&sB[cur ^ 1][arow][akq]      = vb0;
            *(f16x8*)&sB[cur ^ 1][64 + arow][akq] = vb1;
            __syncthreads();
            cur ^= 1;
        }
    }
#pragma unroll
    for (int fi = 0; fi < 2; ++fi)
#pragma unroll
        for (int fj = 0; fj < 4; ++fj) {
            f32x4 d = acc[fi][fj];
#pragma unroll
            for (int r = 0; r < 4; ++r) {
                int i = i0 + wr * 32 + fi * 16 + lr * 4 + r;
                int j = j0 + wc * 64 + fj * 16 + lc;
                size_t o = (size_t)i * NN + j;
                float vv = fmaxf(d[r], 0.f) * (float)xf[o];
                yf[o] = (f16)vv;
            }
        }
}

// ===== K8: LN rows of 256 of (in + in2) -> f32 =============================
__launch_bounds__(256)
__global__ void ln2_kernel(const float* __restrict__ in, const float* __restrict__ in2,
                           float* __restrict__ outf) {
    int wave = threadIdx.x >> 6;
    int lane = threadIdx.x & 63;
    int row  = blockIdx.x * 4 + wave;
    float4 v = *(const float4*)(in + (size_t)row * DD + lane * 4);
    float4 w = *(const float4*)(in2 + (size_t)row * DD + lane * 4);
    v.x += w.x; v.y += w.y; v.z += w.z; v.w += w.w;
    float s  = v.x + v.y + v.z + v.w;
    float s2 = v.x*v.x + v.y*v.y + v.z*v.z + v.w*v.w;
#pragma unroll
    for (int o = 32; o; o >>= 1) {
        s  += __shfl_xor(s,  o, 64);
        s2 += __shfl_xor(s2, o, 64);
    }
    float m  = s * (1.0f / 256.0f);
    float sc = rsqrtf(s2 * (1.0f / 256.0f) - m * m + 1e-5f);
    float4 o4 = {(v.x - m) * sc, (v.y - m) * sc, (v.z - m) * sc, (v.w - m) * sc};
    *(float4*)(outf + (size_t)row * DD + lane * 4) = o4;
}

extern "C" void kernel_launch(void* const* d_in, const int* in_sizes, int n_in,
                              void* d_out, int out_size, void* d_ws, size_t ws_size,
                              hipStream_t stream) {
    (void)in_sizes; (void)n_in; (void)out_size; (void)ws_size;
    const float* emb = (const float*)d_in[0];   // (B,T,d)
    const float* E   = (const float*)d_in[1];   // (d,n)
    const float* Dx  = (const float*)d_in[2];   // (n,d)
    const float* Dy  = (const float*)d_in[3];   // (n,d)
    float* out = (float*)d_out;                 // (B,T,d)

    char* wsb = (char*)d_ws;
    f16*   embf  = (f16*)(wsb + 0);          // 1 MB
    f16*   Ef    = (f16*)(wsb + 1048576);    // 512 KB
    f16*   Dxf   = (f16*)(wsb + 1572864);    // 512 KB
    f16*   Dyf   = (f16*)(wsb + 2097152);    // 512 KB
    f16*   lnvTf = (f16*)(wsb + 2621440);    // 1 MB   [b][j][t]
    f16*   xuh   = (f16*)(wsb + 3670016);    // 4 MB
    f16*   xf    = (f16*)(wsb + 7864320);    // 4 MB
    f16*   Wf    = (f16*)(wsb + 12058624);   // 1 MB
    f16*   alnf  = (f16*)(wsb + 13107200);   // 1 MB
    f16*   yf    = (f16*)(wsb + 14155776);   // 4 MB
    float* vpart = (float*)(wsb + 18350080); // 4 MB (2 x ROWS*DD)
    float* Spart = (float*)(wsb + 22544384); // 64 KB (8 x ROWS)

    // K1: f16 conversions + LN^T(emb)
    cvtln_kernel<<<1280 + ROWS / 16, 256, 0, stream>>>(
        emb, E, Dx, Dy, embf, Ef, Dxf, Dyf, lnvTf);
    // K2: xu = relu(emb @ Dx^T) -> f16 + row-sum partials
    k_xu<<<dim3(NN / 128, ROWS / 64), 256, 0, stream>>>(embf, Dxf, xuh, Spart);
    // K3: x scan (inline normalizer)
    k_xscan<<<BB * (NN / 16), 256, 0, stream>>>(xuh, Spart, xf);
    // K4: W = mask . (X X^T)
    g64_kernel<3><<<dim3(TT / 64, TT / 64, BB), 256, 0, stream>>>(
        xf, xf, nullptr, Wf, TT, NN, NN,
        (long long)TT * NN, (long long)TT * NN, (long long)TT * TT);
    // K5: aln = LN(W @ lnv), 16-row blocks
    k_aln<<<dim3(TT / 16, BB), 256, 0, stream>>>(Wf, lnvTf, alnf);
    // K6: y = relu(aln @ Dy^T) * x
    k_y<<<dim3(NN / 128, ROWS / 64), 256, 0, stream>>>(alnf, Dyf, yf, xf);
    // K7: vpart = y @ E^T split-K=2
    g64_kernel<0><<<dim3(DD / 64, ROWS / 64, 2), 256, 0, stream>>>(
        yf, Ef, vpart, nullptr, DD, NN, 512,
        512LL, 512LL, (long long)ROWS * DD);
    // K8: out = LN(vpart0 + vpart1)
    ln2_kernel<<<ROWS / 4, 256, 0, stream>>>(
        vpart, vpart + (size_t)ROWS * DD, out);
}